// Round 11
// baseline (19577.477 us; speedup 1.0000x reference)
//
#include <hip/hip_runtime.h>

#define HIDDEN   2048
#define T_STEPS  8192
#define WASHOUT  200
#define NWG      64
#define NTHR     512
#define NWAVE    (NTHR / 64)                 // 8 waves
#define ROWS_PER_WG   (HIDDEN / NWG)         // 32
#define ROWS_PER_WAVE (ROWS_PER_WG / NWAVE)  // 4
#define NCHUNK   8                           // 8 chunks of 256 state elements

// ws layout: unsigned long long pairs[2][HIDDEN] -- {step:hi32, value:lo32}.
// One 8B unit carries payload+tag. Freshness via u64 window compare:
// pair in [want<<32, (want+1)<<32)  <=>  hi32 == want, any value bits.
// Stale tags (want-2) fail the lower bound; 0xAA poison (hi32=0xAAAAAAAA)
// fails the upper bound -> self-initializing, no init kernel.

// Weights live in AGPRs (asm-defined: cannot be rematerialized or refetched).
#define AG_W(dst, src) \
  asm volatile("v_accvgpr_write_b32 %0, %1" : "=a"(dst) : "v"(src))
#define AG_R(dst, src) \
  asm("v_accvgpr_read_b32 %0, %1" : "=v"(dst) : "a"(src))

typedef unsigned uint2v __attribute__((ext_vector_type(2)));

#define CHECK4(R0, R1, R2, R3)                          \
  "v_cmp_le_u64 vcc, %[W1], %[" R0 "]\n\t"              \
  "v_cmp_gt_u64 %[tm], %[W2], %[" R0 "]\n\t"            \
  "s_and_b64 vcc, vcc, %[tm]\n\t"                       \
  "v_cmp_le_u64 %[tm], %[W1], %[" R1 "]\n\t"            \
  "s_and_b64 vcc, vcc, %[tm]\n\t"                       \
  "v_cmp_gt_u64 %[tm], %[W2], %[" R1 "]\n\t"            \
  "s_and_b64 vcc, vcc, %[tm]\n\t"                       \
  "v_cmp_le_u64 %[tm], %[W1], %[" R2 "]\n\t"            \
  "s_and_b64 vcc, vcc, %[tm]\n\t"                       \
  "v_cmp_gt_u64 %[tm], %[W2], %[" R2 "]\n\t"            \
  "s_and_b64 vcc, vcc, %[tm]\n\t"                       \
  "v_cmp_le_u64 %[tm], %[W1], %[" R3 "]\n\t"            \
  "s_and_b64 vcc, vcc, %[tm]\n\t"                       \
  "v_cmp_gt_u64 %[tm], %[W2], %[" R3 "]\n\t"            \
  "s_and_b64 vcc, vcc, %[tm]\n\t"                       \
  "s_cmp_eq_u64 vcc, -1\n\t"

#define LOAD4(R0, R1, R2, R3)                                        \
  "global_load_dwordx2 %[" R0 "], %[ad], off sc1\n\t"                \
  "global_load_dwordx2 %[" R1 "], %[ad], off offset:512 sc1\n\t"     \
  "global_load_dwordx2 %[" R2 "], %[ad], off offset:1024 sc1\n\t"    \
  "global_load_dwordx2 %[" R3 "], %[ad], off offset:1536 sc1\n\t"

__global__ __launch_bounds__(NTHR, 1) void esn_main(
    const float* __restrict__ u,
    const float* __restrict__ w_in,
    const float* __restrict__ w_res,
    const float* __restrict__ w_out,
    float* __restrict__ out,
    unsigned long long* __restrict__ pairs)
{
  const int g  = blockIdx.x;    // 0..63, one WG per CU
  const int j  = threadIdx.x;   // 0..511
  const int wv = j >> 6;        // 0..7
  const int l  = j & 63;

  __shared__ float x_s[2][HIDDEN];      // double-buffered staged state (16 KB)
  __shared__ float u_s[T_STEPS];        // 32 KB
  __shared__ float fresh[ROWS_PER_WG];  // this WG's newest 32 values

#pragma unroll
  for (int k = 0; k < T_STEPS / NTHR; ++k) u_s[j + NTHR * k] = u[j + NTHR * k];

  // wave wv owns rows r0..r0+3; lane l owns cols {c*256 + 4l .. +3}
  const int r0 = g * ROWS_PER_WG + wv * ROWS_PER_WAVE;

  float wa[ROWS_PER_WAVE][4 * NCHUNK];  // 128 AGPR-resident weights per thread
#pragma unroll
  for (int i = 0; i < ROWS_PER_WAVE; ++i) {
#pragma unroll
    for (int c = 0; c < NCHUNK; ++c) {
      const float4 a = *(const float4*)&w_res[(r0 + i) * HIDDEN + c * 256 + 4 * l];
      AG_W(wa[i][4 * c + 0], a.x); AG_W(wa[i][4 * c + 1], a.y);
      AG_W(wa[i][4 * c + 2], a.z); AG_W(wa[i][4 * c + 3], a.w);
    }
  }

  const float winl = w_in[r0 + (l & 3)];                             // lanes 0..3
  const float wol  = (wv == 1 && l < 32) ? w_out[g * 32 + l] : 0.f;  // wave 1

  __syncthreads();  // u_s ready

  for (int t = 0; t < T_STEPS; ++t) {
    float d0 = 0.f, d1 = 0.f, d2 = 0.f, d3 = 0.f;
    const unsigned b = (unsigned)((t - 1) & 1);
    if (t > 0) {
      const unsigned want = (unsigned)(t - 1);
      const unsigned long long W1 = ((unsigned long long)want) << 32;
      const unsigned long long W2 = ((unsigned long long)(want + 1)) << 32;
      // lane l polls chunk elements {l, l+64, l+128, l+192}: each load instr
      // covers 512B contiguous (8 lines). 2-deep pipelined: 2 rounds in
      // flight, s_waitcnt vmcnt(4) alternation -> sampling interval ~RT/2.
      const unsigned long long ad =
          (unsigned long long)(pairs + b * HIDDEN + (wv << 8) + l);
      uint2v A0, A1, A2, A3, B0, B1, B2, B3;
      unsigned long long tm;
      asm volatile(
          LOAD4("A0", "A1", "A2", "A3")
          "LPOLL%=:\n\t"
          LOAD4("B0", "B1", "B2", "B3")
          "s_waitcnt vmcnt(4)\n\t"          // A-round landed
          CHECK4("A0", "A1", "A2", "A3")
          "s_cbranch_scc1 LDONEA%=\n\t"
          LOAD4("A0", "A1", "A2", "A3")
          "s_waitcnt vmcnt(4)\n\t"          // B-round landed
          CHECK4("B0", "B1", "B2", "B3")
          "s_cbranch_scc0 LPOLL%=\n\t"
          "s_waitcnt vmcnt(0)\n\t"          // drain pending A before moving B->A
          "v_lshlrev_b64 %[A0], 0, %[B0]\n\t"
          "v_lshlrev_b64 %[A1], 0, %[B1]\n\t"
          "v_lshlrev_b64 %[A2], 0, %[B2]\n\t"
          "v_lshlrev_b64 %[A3], 0, %[B3]\n\t"
          "s_branch LEND%=\n\t"
          "LDONEA%=:\n\t"
          "s_waitcnt vmcnt(0)\n\t"          // drain pending B (reg-reuse safety)
          "LEND%=:\n\t"
          : [A0] "=&v"(A0), [A1] "=&v"(A1), [A2] "=&v"(A2), [A3] "=&v"(A3),
            [B0] "=&v"(B0), [B1] "=&v"(B1), [B2] "=&v"(B2), [B3] "=&v"(B3),
            [tm] "=&s"(tm)
          : [ad] "v"(ad), [W1] "s"(W1), [W2] "s"(W2)
          : "vcc", "scc", "memory");
      // value is the LOW dword of each pair
      float* xr = &x_s[b][(wv << 8) + l];
      xr[0]   = __uint_as_float(A0.x);
      xr[64]  = __uint_as_float(A1.x);
      xr[128] = __uint_as_float(A2.x);
      xr[192] = __uint_as_float(A3.x);
    }
    __syncthreads();  // barrier 1: all chunks staged

    if (t > 0) {
      const float4* xs4 = (const float4*)x_s[b];
#pragma unroll
      for (int c = 0; c < NCHUNK; ++c) {
        const float4 x4 = xs4[(c << 6) + l];   // ds_read_b128
        float w;
        AG_R(w, wa[0][4 * c + 0]); d0 = fmaf(w, x4.x, d0);
        AG_R(w, wa[0][4 * c + 1]); d0 = fmaf(w, x4.y, d0);
        AG_R(w, wa[0][4 * c + 2]); d0 = fmaf(w, x4.z, d0);
        AG_R(w, wa[0][4 * c + 3]); d0 = fmaf(w, x4.w, d0);
        AG_R(w, wa[1][4 * c + 0]); d1 = fmaf(w, x4.x, d1);
        AG_R(w, wa[1][4 * c + 1]); d1 = fmaf(w, x4.y, d1);
        AG_R(w, wa[1][4 * c + 2]); d1 = fmaf(w, x4.z, d1);
        AG_R(w, wa[1][4 * c + 3]); d1 = fmaf(w, x4.w, d1);
        AG_R(w, wa[2][4 * c + 0]); d2 = fmaf(w, x4.x, d2);
        AG_R(w, wa[2][4 * c + 1]); d2 = fmaf(w, x4.y, d2);
        AG_R(w, wa[2][4 * c + 2]); d2 = fmaf(w, x4.z, d2);
        AG_R(w, wa[2][4 * c + 3]); d2 = fmaf(w, x4.w, d2);
        AG_R(w, wa[3][4 * c + 0]); d3 = fmaf(w, x4.x, d3);
        AG_R(w, wa[3][4 * c + 1]); d3 = fmaf(w, x4.y, d3);
        AG_R(w, wa[3][4 * c + 2]); d3 = fmaf(w, x4.z, d3);
        AG_R(w, wa[3][4 * c + 3]); d3 = fmaf(w, x4.w, d3);
      }
    }

    // tree-combine reduce: 10 shuffles; lane l ends with row (l&3)'s full sum
    float e0 = d0 + __shfl_xor(d0, 1, 64);
    float e1 = d1 + __shfl_xor(d1, 1, 64);
    float e2 = d2 + __shfl_xor(d2, 1, 64);
    float e3 = d3 + __shfl_xor(d3, 1, 64);
    float f0 = (l & 1) ? e1 : e0;
    float f1 = (l & 1) ? e3 : e2;
    f0 += __shfl_xor(f0, 2, 64);
    f1 += __shfl_xor(f1, 2, 64);
    float h = (l & 2) ? f1 : f0;
    h += __shfl_xor(h, 4, 64);
    h += __shfl_xor(h, 8, 64);
    h += __shfl_xor(h, 16, 64);
    h += __shfl_xor(h, 32, 64);

    const float ut = u_s[t];
    if (l < ROWS_PER_WAVE) {
      fresh[wv * ROWS_PER_WAVE + l] = tanhf(fmaf(winl, ut, h));
    }
    __syncthreads();  // barrier 2: fresh[] complete

    if (wv == 0) {
      // consolidated publish: one 32-lane 256B store for the whole WG
      if (l < ROWS_PER_WG) {
        const unsigned long long pk =
            (((unsigned long long)(unsigned)t) << 32) |
            (unsigned long long)__float_as_uint(fresh[l]);
        __hip_atomic_store(pairs + (t & 1) * HIDDEN + g * ROWS_PER_WG + l, pk,
                           __ATOMIC_RELAXED, __HIP_MEMORY_SCOPE_AGENT);
      }
    } else if (wv == 1 && t >= WASHOUT) {
      // distributed readout: this WG's 32-row partial of x_t . w_out
      float part = (l < 32) ? fresh[l] * wol : 0.f;
      part += __shfl_xor(part, 32, 64);
      part += __shfl_xor(part, 16, 64);
      part += __shfl_xor(part, 8, 64);
      part += __shfl_xor(part, 4, 64);
      part += __shfl_xor(part, 2, 64);
      part += __shfl_xor(part, 1, 64);
      if (l == 0) atomicAdd(&out[t - WASHOUT], part);
    }
  }
}

extern "C" void kernel_launch(void* const* d_in, const int* in_sizes, int n_in,
                              void* d_out, int out_size, void* d_ws, size_t ws_size,
                              hipStream_t stream) {
  const float* u     = (const float*)d_in[0];
  const float* w_in  = (const float*)d_in[1];
  const float* w_res = (const float*)d_in[2];
  const float* w_out = (const float*)d_in[3];
  float* out = (float*)d_out;
  unsigned long long* pairs = (unsigned long long*)d_ws;

  // out accumulates atomicAdd partials -> must start at zero every call
  hipMemsetAsync(out, 0, (size_t)out_size * sizeof(float), stream);
  esn_main<<<NWG, NTHR, 0, stream>>>(u, w_in, w_res, w_out, out, pairs);
}

// Round 12
// 19131.065 us; speedup vs baseline: 1.0233x; 1.0233x over previous
//
#include <hip/hip_runtime.h>

#define HIDDEN   2048
#define T_STEPS  8192
#define WASHOUT  200
#define NWG      64
#define NTHR     512
#define NWAVE    (NTHR / 64)                 // 8 waves
#define ROWS_PER_WG   (HIDDEN / NWG)         // 32
#define ROWS_PER_WAVE (ROWS_PER_WG / NWAVE)  // 4
#define NCHUNK   8                           // 8 chunks of 256 state elements
#define NREP     8                           // publish replicas (bank spreading)

// ws layout: unsigned long long pairs[2][NREP][HIDDEN] -- {value:hi32, step:lo32}.
// All 8 waves of a WG publish its fresh 32-pair block, wave wv -> replica wv
// (parallel 256B stores). Consumer WG g polls ONLY replica g&7: per-replica
// poller herd is 8 WGs instead of 64 -> 8x less L3 hot-bank queueing.
// 0xAA poison: step field 0xAAAAAAAA never matches a real step (self-init).

// Weights live in AGPRs (asm-defined: cannot be rematerialized or refetched).
#define AG_W(dst, src) \
  asm volatile("v_accvgpr_write_b32 %0, %1" : "=a"(dst) : "v"(src))
#define AG_R(dst, src) \
  asm("v_accvgpr_read_b32 %0, %1" : "=v"(dst) : "a"(src))

typedef unsigned uint4v __attribute__((ext_vector_type(4)));

__global__ __launch_bounds__(NTHR, 1) void esn_main(
    const float* __restrict__ u,
    const float* __restrict__ w_in,
    const float* __restrict__ w_res,
    const float* __restrict__ w_out,
    float* __restrict__ out,
    unsigned long long* __restrict__ pairs)
{
  const int g  = blockIdx.x;    // 0..63, one WG per CU
  const int j  = threadIdx.x;   // 0..511
  const int wv = j >> 6;        // 0..7
  const int l  = j & 63;
  const int rep = g & (NREP - 1);   // this WG's poll replica

  __shared__ float x_s[2][HIDDEN];      // double-buffered staged state (16 KB)
  __shared__ float u_s[T_STEPS];        // 32 KB
  __shared__ float fresh[ROWS_PER_WG];  // this WG's newest 32 values

#pragma unroll
  for (int k = 0; k < T_STEPS / NTHR; ++k) u_s[j + NTHR * k] = u[j + NTHR * k];

  // wave wv owns rows r0..r0+3; lane l owns cols {c*256 + 4l .. +3}
  const int r0 = g * ROWS_PER_WG + wv * ROWS_PER_WAVE;

  float wa[ROWS_PER_WAVE][4 * NCHUNK];  // 128 AGPR-resident weights per thread
#pragma unroll
  for (int i = 0; i < ROWS_PER_WAVE; ++i) {
#pragma unroll
    for (int c = 0; c < NCHUNK; ++c) {
      const float4 a = *(const float4*)&w_res[(r0 + i) * HIDDEN + c * 256 + 4 * l];
      AG_W(wa[i][4 * c + 0], a.x); AG_W(wa[i][4 * c + 1], a.y);
      AG_W(wa[i][4 * c + 2], a.z); AG_W(wa[i][4 * c + 3], a.w);
    }
  }

  const float winl = w_in[r0 + (l & 3)];                             // lanes 0..3
  const float wol  = (wv == 1 && l < 32) ? w_out[g * 32 + l] : 0.f;  // wave 1

  __syncthreads();  // u_s ready

  for (int t = 0; t < T_STEPS; ++t) {
    float d0 = 0.f, d1 = 0.f, d2 = 0.f, d3 = 0.f;
    const unsigned b = (unsigned)((t - 1) & 1);
    if (t > 0) {
      const unsigned want = (unsigned)(t - 1);
      // wave wv polls its chunk of THIS WG's replica; 2x16B loads per round
      const unsigned long long* bp =
          pairs + (b * NREP + rep) * HIDDEN + (wv << 8) + 4 * l;
      uint4v A, B;   // [tag0, val0, tag1, val1]
      for (;;) {
        asm volatile(
            "global_load_dwordx4 %0, %2, off sc1\n\t"
            "global_load_dwordx4 %1, %3, off sc1\n\t"
            "s_waitcnt vmcnt(0)"
            : "=&v"(A), "=&v"(B)
            : "v"(bp), "v"(bp + 2)
            : "memory");
        if (((A.x == want) & (A.z == want)) &
            ((B.x == want) & (B.z == want))) break;
      }
      float4 xv;
      xv.x = __uint_as_float(A.y);
      xv.y = __uint_as_float(A.w);
      xv.z = __uint_as_float(B.y);
      xv.w = __uint_as_float(B.w);
      *(float4*)&x_s[b][(wv << 8) + 4 * l] = xv;  // one ds_write_b128
    }
    __syncthreads();  // barrier 1: all chunks staged

    if (t > 0) {
      const float4* xs4 = (const float4*)x_s[b];
#pragma unroll
      for (int c = 0; c < NCHUNK; ++c) {
        const float4 x4 = xs4[(c << 6) + l];   // ds_read_b128
        float w;
        AG_R(w, wa[0][4 * c + 0]); d0 = fmaf(w, x4.x, d0);
        AG_R(w, wa[0][4 * c + 1]); d0 = fmaf(w, x4.y, d0);
        AG_R(w, wa[0][4 * c + 2]); d0 = fmaf(w, x4.z, d0);
        AG_R(w, wa[0][4 * c + 3]); d0 = fmaf(w, x4.w, d0);
        AG_R(w, wa[1][4 * c + 0]); d1 = fmaf(w, x4.x, d1);
        AG_R(w, wa[1][4 * c + 1]); d1 = fmaf(w, x4.y, d1);
        AG_R(w, wa[1][4 * c + 2]); d1 = fmaf(w, x4.z, d1);
        AG_R(w, wa[1][4 * c + 3]); d1 = fmaf(w, x4.w, d1);
        AG_R(w, wa[2][4 * c + 0]); d2 = fmaf(w, x4.x, d2);
        AG_R(w, wa[2][4 * c + 1]); d2 = fmaf(w, x4.y, d2);
        AG_R(w, wa[2][4 * c + 2]); d2 = fmaf(w, x4.z, d2);
        AG_R(w, wa[2][4 * c + 3]); d2 = fmaf(w, x4.w, d2);
        AG_R(w, wa[3][4 * c + 0]); d3 = fmaf(w, x4.x, d3);
        AG_R(w, wa[3][4 * c + 1]); d3 = fmaf(w, x4.y, d3);
        AG_R(w, wa[3][4 * c + 2]); d3 = fmaf(w, x4.z, d3);
        AG_R(w, wa[3][4 * c + 3]); d3 = fmaf(w, x4.w, d3);
      }
    }

    // tree-combine reduce: 10 shuffles; lane l ends with row (l&3)'s full sum
    float e0 = d0 + __shfl_xor(d0, 1, 64);
    float e1 = d1 + __shfl_xor(d1, 1, 64);
    float e2 = d2 + __shfl_xor(d2, 1, 64);
    float e3 = d3 + __shfl_xor(d3, 1, 64);
    float f0 = (l & 1) ? e1 : e0;
    float f1 = (l & 1) ? e3 : e2;
    f0 += __shfl_xor(f0, 2, 64);
    f1 += __shfl_xor(f1, 2, 64);
    float h = (l & 2) ? f1 : f0;
    h += __shfl_xor(h, 4, 64);
    h += __shfl_xor(h, 8, 64);
    h += __shfl_xor(h, 16, 64);
    h += __shfl_xor(h, 32, 64);

    const float ut = u_s[t];
    if (l < ROWS_PER_WAVE) {
      fresh[wv * ROWS_PER_WAVE + l] = tanhf(fmaf(winl, ut, h));
    }
    __syncthreads();  // barrier 2: fresh[] complete

    // replicated publish: wave wv stores the WG's 32-pair block to replica wv
    // (8 parallel 256B stores chip-wide per WG)
    if (l < ROWS_PER_WG) {
      const unsigned long long pk =
          ((unsigned long long)__float_as_uint(fresh[l]) << 32) | (unsigned)t;
      __hip_atomic_store(
          pairs + ((t & 1) * NREP + wv) * HIDDEN + g * ROWS_PER_WG + l, pk,
          __ATOMIC_RELAXED, __HIP_MEMORY_SCOPE_AGENT);
    }
    if (wv == 1 && t >= WASHOUT) {
      // distributed readout: this WG's 32-row partial of x_t . w_out
      float part = (l < 32) ? fresh[l] * wol : 0.f;
      part += __shfl_xor(part, 32, 64);
      part += __shfl_xor(part, 16, 64);
      part += __shfl_xor(part, 8, 64);
      part += __shfl_xor(part, 4, 64);
      part += __shfl_xor(part, 2, 64);
      part += __shfl_xor(part, 1, 64);
      if (l == 0) atomicAdd(&out[t - WASHOUT], part);
    }
  }
}

extern "C" void kernel_launch(void* const* d_in, const int* in_sizes, int n_in,
                              void* d_out, int out_size, void* d_ws, size_t ws_size,
                              hipStream_t stream) {
  const float* u     = (const float*)d_in[0];
  const float* w_in  = (const float*)d_in[1];
  const float* w_res = (const float*)d_in[2];
  const float* w_out = (const float*)d_in[3];
  float* out = (float*)d_out;
  unsigned long long* pairs = (unsigned long long*)d_ws;

  // out accumulates atomicAdd partials -> must start at zero every call
  hipMemsetAsync(out, 0, (size_t)out_size * sizeof(float), stream);
  esn_main<<<NWG, NTHR, 0, stream>>>(u, w_in, w_res, w_out, out, pairs);
}

// Round 14
// 17655.060 us; speedup vs baseline: 1.1089x; 1.0836x over previous
//
#include <hip/hip_runtime.h>

#define HIDDEN   2048
#define T_STEPS  8192
#define WASHOUT  200
#define NWG      64
#define NTHR     512
#define NWAVE    (NTHR / 64)                 // 8 waves
#define ROWS_PER_WG   (HIDDEN / NWG)         // 32
#define ROWS_PER_WAVE (ROWS_PER_WG / NWAVE)  // 4
#define NCHUNK   8                           // 8 chunks of 256 state elements

// ws layout: unsigned long long pairs[2][HIDDEN] -- {value:hi32, step:lo32}.
// One 8B unit carries payload+tag: no fences, no flags, one round trip.
// 0xAA poison: step field 0xAAAAAAAA never matches a real step (self-init).

// Weights live in AGPRs (asm-defined: cannot be rematerialized or refetched).
// NOTE (R13 lesson): gfx950 VALU cannot source AGPRs directly -- v_fmac_f32
// with an 'a' operand is rejected by the assembler. AG_R + fmaf is minimal.
#define AG_W(dst, src) \
  asm volatile("v_accvgpr_write_b32 %0, %1" : "=a"(dst) : "v"(src))
#define AG_R(dst, src) \
  asm("v_accvgpr_read_b32 %0, %1" : "=v"(dst) : "a"(src))

// DPP add: x + dpp_perm(x). All-VALU (no DS round trip).
#define DPP_ADD(x, ctrl) ((x) + __int_as_float(__builtin_amdgcn_update_dpp( \
    0, __float_as_int(x), ctrl, 0xF, 0xF, true)))

typedef unsigned uint4v __attribute__((ext_vector_type(4)));

__global__ __launch_bounds__(NTHR, 1) void esn_main(
    const float* __restrict__ u,
    const float* __restrict__ w_in,
    const float* __restrict__ w_res,
    const float* __restrict__ w_out,
    float* __restrict__ out,
    unsigned long long* __restrict__ pairs)
{
  const int g  = blockIdx.x;    // 0..63, one WG per CU
  const int j  = threadIdx.x;   // 0..511
  const int wv = j >> 6;        // 0..7
  const int l  = j & 63;

  __shared__ float x_s[2][HIDDEN];      // double-buffered staged state (16 KB)
  __shared__ float u_s[T_STEPS];        // 32 KB
  __shared__ float fresh[ROWS_PER_WG];  // this WG's newest 32 values

#pragma unroll
  for (int k = 0; k < T_STEPS / NTHR; ++k) u_s[j + NTHR * k] = u[j + NTHR * k];

  // wave wv owns rows r0..r0+3; lane l owns cols {c*256 + 4l .. +3}
  const int r0 = g * ROWS_PER_WG + wv * ROWS_PER_WAVE;

  float wa[ROWS_PER_WAVE][4 * NCHUNK];  // 128 AGPR-resident weights per thread
#pragma unroll
  for (int i = 0; i < ROWS_PER_WAVE; ++i) {
#pragma unroll
    for (int c = 0; c < NCHUNK; ++c) {
      const float4 a = *(const float4*)&w_res[(r0 + i) * HIDDEN + c * 256 + 4 * l];
      AG_W(wa[i][4 * c + 0], a.x); AG_W(wa[i][4 * c + 1], a.y);
      AG_W(wa[i][4 * c + 2], a.z); AG_W(wa[i][4 * c + 3], a.w);
    }
  }

  const float winl = w_in[r0 + (l & 3)];                             // lanes 0..3
  const float wol  = (wv == 1 && l < 32) ? w_out[g * 32 + l] : 0.f;  // wave 1

  __syncthreads();  // u_s ready

  for (int t = 0; t < T_STEPS; ++t) {
    float d0 = 0.f, d1 = 0.f, d2 = 0.f, d3 = 0.f;
    const unsigned b = (unsigned)((t - 1) & 1);
    if (t > 0) {
      const unsigned want = (unsigned)(t - 1);
      // wave wv polls only its own chunk; 2x16B L2-bypassing loads per round
      const unsigned long long* bp = pairs + b * HIDDEN + (wv << 8) + 4 * l;
      uint4v A, B;   // [tag0, val0, tag1, val1]
      for (;;) {
        asm volatile(
            "global_load_dwordx4 %0, %2, off sc1\n\t"
            "global_load_dwordx4 %1, %3, off sc1\n\t"
            "s_waitcnt vmcnt(0)"
            : "=&v"(A), "=&v"(B)
            : "v"(bp), "v"(bp + 2)
            : "memory");
        if (((A.x == want) & (A.z == want)) &
            ((B.x == want) & (B.z == want))) break;
      }
      float4 xv;
      xv.x = __uint_as_float(A.y);
      xv.y = __uint_as_float(A.w);
      xv.z = __uint_as_float(B.y);
      xv.w = __uint_as_float(B.w);
      *(float4*)&x_s[b][(wv << 8) + 4 * l] = xv;  // one ds_write_b128
    }
    __syncthreads();  // barrier 1: all chunks staged

    if (t > 0) {
      const float4* xs4 = (const float4*)x_s[b];
#pragma unroll
      for (int c = 0; c < NCHUNK; ++c) {
        const float4 x4 = xs4[(c << 6) + l];   // ds_read_b128
        float w;
        AG_R(w, wa[0][4 * c + 0]); d0 = fmaf(w, x4.x, d0);
        AG_R(w, wa[0][4 * c + 1]); d0 = fmaf(w, x4.y, d0);
        AG_R(w, wa[0][4 * c + 2]); d0 = fmaf(w, x4.z, d0);
        AG_R(w, wa[0][4 * c + 3]); d0 = fmaf(w, x4.w, d0);
        AG_R(w, wa[1][4 * c + 0]); d1 = fmaf(w, x4.x, d1);
        AG_R(w, wa[1][4 * c + 1]); d1 = fmaf(w, x4.y, d1);
        AG_R(w, wa[1][4 * c + 2]); d1 = fmaf(w, x4.z, d1);
        AG_R(w, wa[1][4 * c + 3]); d1 = fmaf(w, x4.w, d1);
        AG_R(w, wa[2][4 * c + 0]); d2 = fmaf(w, x4.x, d2);
        AG_R(w, wa[2][4 * c + 1]); d2 = fmaf(w, x4.y, d2);
        AG_R(w, wa[2][4 * c + 2]); d2 = fmaf(w, x4.z, d2);
        AG_R(w, wa[2][4 * c + 3]); d2 = fmaf(w, x4.w, d2);
        AG_R(w, wa[3][4 * c + 0]); d3 = fmaf(w, x4.x, d3);
        AG_R(w, wa[3][4 * c + 1]); d3 = fmaf(w, x4.y, d3);
        AG_R(w, wa[3][4 * c + 2]); d3 = fmaf(w, x4.z, d3);
        AG_R(w, wa[3][4 * c + 3]); d3 = fmaf(w, x4.w, d3);
      }
    }

    // reduce: DPP for intra-16 steps (VALU latency), shuffles only for 16/32.
    // quad sums -> selects -> row_ror:4 + row_ror:8 give per-16-group sums,
    // then 2 shuffles complete the 64-lane row sums (same placement as R9).
    float e0 = DPP_ADD(d0, 0xB1);   // quad_perm [1,0,3,2]  (xor 1)
    float e1 = DPP_ADD(d1, 0xB1);
    float e2 = DPP_ADD(d2, 0xB1);
    float e3 = DPP_ADD(d3, 0xB1);
    float f0 = (l & 1) ? e1 : e0;
    float f1 = (l & 1) ? e3 : e2;
    f0 = DPP_ADD(f0, 0x4E);         // quad_perm [2,3,0,1]  (xor 2)
    f1 = DPP_ADD(f1, 0x4E);
    float h = (l & 2) ? f1 : f0;
    h = DPP_ADD(h, 0x124);          // row_ror:4
    h = DPP_ADD(h, 0x128);          // row_ror:8
    h += __shfl_xor(h, 16, 64);
    h += __shfl_xor(h, 32, 64);

    const float ut = u_s[t];
    if (l < ROWS_PER_WAVE) {
      fresh[wv * ROWS_PER_WAVE + l] = tanhf(fmaf(winl, ut, h));
    }
    __syncthreads();  // barrier 2: fresh[] complete

    if (wv == 0) {
      // consolidated publish: one 32-lane 256B store for the whole WG
      if (l < ROWS_PER_WG) {
        const unsigned long long pk =
            ((unsigned long long)__float_as_uint(fresh[l]) << 32) | (unsigned)t;
        __hip_atomic_store(pairs + (t & 1) * HIDDEN + g * ROWS_PER_WG + l, pk,
                           __ATOMIC_RELAXED, __HIP_MEMORY_SCOPE_AGENT);
      }
    } else if (wv == 1 && t >= WASHOUT) {
      // distributed readout: this WG's 32-row partial of x_t . w_out
      float part = (l < 32) ? fresh[l] * wol : 0.f;
      part += __shfl_xor(part, 32, 64);
      part += __shfl_xor(part, 16, 64);
      part += __shfl_xor(part, 8, 64);
      part += __shfl_xor(part, 4, 64);
      part += __shfl_xor(part, 2, 64);
      part += __shfl_xor(part, 1, 64);
      if (l == 0) atomicAdd(&out[t - WASHOUT], part);
    }
  }
}

extern "C" void kernel_launch(void* const* d_in, const int* in_sizes, int n_in,
                              void* d_out, int out_size, void* d_ws, size_t ws_size,
                              hipStream_t stream) {
  const float* u     = (const float*)d_in[0];
  const float* w_in  = (const float*)d_in[1];
  const float* w_res = (const float*)d_in[2];
  const float* w_out = (const float*)d_in[3];
  float* out = (float*)d_out;
  unsigned long long* pairs = (unsigned long long*)d_ws;

  // out accumulates atomicAdd partials -> must start at zero every call
  hipMemsetAsync(out, 0, (size_t)out_size * sizeof(float), stream);
  esn_main<<<NWG, NTHR, 0, stream>>>(u, w_in, w_res, w_out, out, pairs);
}